// Round 4
// baseline (184.568 us; speedup 1.0000x reference)
//
#include <hip/hip_runtime.h>
#include <math.h>

#define HDIM 256
#define PDIM 256
#define BATCH 8
#define LSEQ 4096
#define MTOT (BATCH * LSEQ)   // 32768
#define CHLEN 128             // chunk = one 128-row M-tile
#define NCHUNK 32             // LSEQ / CHLEN

typedef __attribute__((ext_vector_type(8))) short bf16x8;   // 8 bf16 = 4 VGPRs
typedef __attribute__((ext_vector_type(4))) float f32x4;

__device__ __forceinline__ unsigned short f2bf(float f) {
    union { float f; unsigned int u; } v; v.f = f;
    unsigned int r = v.u + 0x7FFFu + ((v.u >> 16) & 1u);   // RNE
    return (unsigned short)(r >> 16);
}
__device__ __forceinline__ float bf2f(unsigned int lo16) {
    union { unsigned int u; float f; } v; v.u = lo16 << 16;
    return v.f;
}

// ---------------- params: a (par[0:512)), apw[j][2p] = a^{j+1}, j=0..127 ----------------
__global__ void params_k(const float* __restrict__ llr, const float* __restrict__ lim,
                         const float* __restrict__ ldl, float* __restrict__ par,
                         float* __restrict__ apw) {
    int p = threadIdx.x;
    float er = expf(llr[p]);          // -Re(lam) > 0
    float im = lim[p];
    float d  = expf(ldl[p]);
    float zr = -er * d, zi = im * d;  // lam*delta
    float ea = expf(zr);
    float ar = ea * cosf(zi), ai = ea * sinf(zi);   // a = exp(lam*delta)
    par[2 * p]     = ar;
    par[2 * p + 1] = ai;
    float pr = ar, pi = ai;
    apw[2 * p] = pr; apw[2 * p + 1] = pi;           // a^1
    for (int j = 1; j < CHLEN; j++) {
        float nr = pr * ar - pi * ai;
        float ni = pr * ai + pi * ar;
        pr = nr; pi = ni;
        apw[j * 512 + 2 * p]     = pr;              // a^{j+1}
        apw[j * 512 + 2 * p + 1] = pi;
    }
}

// W1t[n][k] (bf16 [512][256]): n=2p -> Re(coef_p*B[p][k]), n=2p+1 -> Im.
// W2t[h][2p] = Cr[h][p]; W2t[h][2p+1] = -Ci[h][p]  (bf16 [256][512]).
__global__ void w12_k(const float* __restrict__ Br, const float* __restrict__ Bi,
                      const float* __restrict__ Cr, const float* __restrict__ Ci,
                      const float* __restrict__ llr, const float* __restrict__ lim,
                      const float* __restrict__ ldl,
                      unsigned short* __restrict__ W1t, unsigned short* __restrict__ W2t) {
    int p = blockIdx.x, h = threadIdx.x;
    float er = expf(llr[p]);
    float im = lim[p];
    float d  = expf(ldl[p]);
    float zr = -er * d, zi = im * d;
    float ea = expf(zr);
    float ar = ea * cosf(zi), ai = ea * sinf(zi);
    float dr = -er, di = im;
    float den = dr * dr + di * di;
    float nr = ar - 1.0f, ni = ai;
    float cr = (nr * dr + ni * di) / den;           // coef = (a-1)/lam
    float ci = (ni * dr - nr * di) / den;
    float br = Br[p * HDIM + h], bi = Bi[p * HDIM + h];
    W1t[(2 * p) * HDIM + h]     = f2bf(cr * br - ci * bi);
    W1t[(2 * p + 1) * HDIM + h] = f2bf(cr * bi + ci * br);
    W2t[h * 512 + 2 * p]     = f2bf(Cr[h * PDIM + p]);
    W2t[h * 512 + 2 * p + 1] = f2bf(-Ci[h * PDIM + p]);
}

// ---------------- fused LayerNorm -> bf16 h ----------------
__global__ void ln_k(const float* __restrict__ u, unsigned short* __restrict__ hbf,
                     const float* __restrict__ gamma, const float* __restrict__ beta) {
    __shared__ float gS[HDIM], bS[HDIM];
    int t = threadIdx.x;
    gS[t] = gamma[t]; bS[t] = beta[t];
    int lane = t & 63, wv = t >> 6;
    int row = blockIdx.x * 4 + wv;
    float4 v = *(const float4*)(u + (size_t)row * HDIM + lane * 4);
    float s  = v.x + v.y + v.z + v.w;
    float sq = v.x * v.x + v.y * v.y + v.z * v.z + v.w * v.w;
    #pragma unroll
    for (int o = 1; o < 64; o <<= 1) { s += __shfl_xor(s, o); sq += __shfl_xor(sq, o); }
    float mu = s * (1.0f / HDIM);
    float rs = rsqrtf(sq * (1.0f / HDIM) - mu * mu + 1e-5f);
    __syncthreads();
    int c = lane * 4;
    ushort4 o;
    o.x = f2bf((v.x - mu) * rs * gS[c + 0] + bS[c + 0]);
    o.y = f2bf((v.y - mu) * rs * gS[c + 1] + bS[c + 1]);
    o.z = f2bf((v.z - mu) * rs * gS[c + 2] + bS[c + 2]);
    o.w = f2bf((v.w - mu) * rs * gS[c + 3] + bS[c + 3]);
    *(ushort4*)(hbf + (size_t)row * HDIM + c) = o;
}

// ---------------- GEMM1 + chunk-local scan (zero-seeded) ----------------
// Stores xloc[M][512] (locally-scanned Bu) and last[bm][p] = xloc[127] (fp32).
__launch_bounds__(256, 2)
__global__ void gemm1_k(const unsigned short* __restrict__ A, const unsigned short* __restrict__ B,
                        unsigned short* __restrict__ Bu, float* __restrict__ last,
                        const float* __restrict__ par, const float* __restrict__ apw) {
    __shared__ union {
        struct { unsigned short A[128 * 32]; unsigned short B[128 * 32]; } st;  // 16 KB
        unsigned short C[128 * 128];                                            // 32 KB
    } sm;

    const int t = threadIdx.x;
    const int bn = blockIdx.x, bm = blockIdx.y;
    const int lane = t & 63;
    const int wm = ((t >> 6) & 1) * 64;
    const int wn = ((t >> 6) >> 1) * 64;
    const int srow = t >> 1, skoff = (t & 1) * 16;
    const unsigned short* Ap = A + (size_t)(bm * 128 + srow) * 256 + skoff;
    const unsigned short* Bp = B + (size_t)(bn * 128 + srow) * 256 + skoff;
    const int mrow = lane & 15, kq = (lane >> 4) * 8;

    f32x4 acc[4][4] = {};

    for (int k0 = 0; k0 < 256; k0 += 32) {
        uint4 a0 = *(const uint4*)(Ap + k0);
        uint4 a1 = *(const uint4*)(Ap + k0 + 8);
        uint4 b0 = *(const uint4*)(Bp + k0);
        uint4 b1 = *(const uint4*)(Bp + k0 + 8);
        __syncthreads();
        *(uint4*)&sm.st.A[srow * 32 + skoff]     = a0;
        *(uint4*)&sm.st.A[srow * 32 + skoff + 8] = a1;
        *(uint4*)&sm.st.B[srow * 32 + skoff]     = b0;
        *(uint4*)&sm.st.B[srow * 32 + skoff + 8] = b1;
        __syncthreads();
        bf16x8 fa[4], fb[4];
        #pragma unroll
        for (int i = 0; i < 4; i++) {
            fa[i] = *(const bf16x8*)&sm.st.A[(wm + i * 16 + mrow) * 32 + kq];
            fb[i] = *(const bf16x8*)&sm.st.B[(wn + i * 16 + mrow) * 32 + kq];
        }
        #pragma unroll
        for (int i = 0; i < 4; i++)
            #pragma unroll
            for (int j = 0; j < 4; j++)
                acc[i][j] = __builtin_amdgcn_mfma_f32_16x16x32_bf16(fa[i], fb[j], acc[i][j], 0, 0, 0);
    }

    __syncthreads();   // done with st; reuse as C
    const int r0 = (lane >> 4) * 4, c0 = lane & 15;
    #pragma unroll
    for (int i = 0; i < 4; i++)
        #pragma unroll
        for (int j = 0; j < 4; j++)
            #pragma unroll
            for (int r = 0; r < 4; r++)
                sm.C[(wm + i * 16 + r0 + r) * 128 + wn + j * 16 + c0] = f2bf(acc[i][j][r]);
    __syncthreads();

    // zero-seeded local scan over the tile's 128 rows (time), one thread per complex col.
    // word index s*64 + t: 64 consecutive words per step -> 2-way bank alias (free).
    if (t < 64) {
        int pg = bn * 64 + t;
        float ar = par[2 * pg], ai = par[2 * pg + 1];
        float xr = 0.0f, xi = 0.0f;
        unsigned int* Cw = (unsigned int*)sm.C;
        #pragma unroll 8
        for (int s = 0; s < CHLEN; s++) {
            unsigned int v = Cw[s * 64 + t];
            float vr = bf2f(v & 0xFFFFu), vi = bf2f(v >> 16);
            float nr = fmaf(ar, xr, fmaf(-ai, xi, vr));
            float ni = fmaf(ar, xi, fmaf(ai, xr, vi));
            xr = nr; xi = ni;
            Cw[s * 64 + t] = (unsigned int)f2bf(xr) | ((unsigned int)f2bf(xi) << 16);
        }
        *(float2*)(last + (size_t)(bm * 256 + pg) * 2) = make_float2(xr, xi);  // fp32 chunk final
    }
    __syncthreads();

    // coalesced store of the scanned tile (xloc) to Bu
    {
        int row = t >> 1, ch = (t & 1) * 64;
        unsigned short* dst = Bu + (size_t)(bm * 128 + row) * 512 + bn * 128 + ch;
        const unsigned short* src = &sm.C[row * 128 + ch];
        #pragma unroll
        for (int q = 0; q < 8; q++)
            *(uint4*)(dst + q * 8) = *(const uint4*)(src + q * 8);
    }
}

// ---------------- carry across chunks; prefix[bm][p] = state entering chunk ----------------
__global__ void carry_k(const float* __restrict__ last, float* __restrict__ prefix,
                        const float* __restrict__ apw) {
    int p = threadIdx.x, b = blockIdx.x;
    float Ar = apw[127 * 512 + 2 * p], Ai = apw[127 * 512 + 2 * p + 1];  // a^128
    float Pr = 0.0f, Pi = 0.0f;
    for (int c = 0; c < NCHUNK; c++) {
        size_t idx = (size_t)((b * NCHUNK + c) * 256 + p) * 2;
        *(float2*)(prefix + idx) = make_float2(Pr, Pi);
        float2 l = *(const float2*)(last + idx);
        float nr = fmaf(Ar, Pr, fmaf(-Ai, Pi, l.x));
        float ni = fmaf(Ar, Pi, fmaf(Ai, Pr, l.y));
        Pr = nr; Pi = ni;
    }
}

// ---------------- GEMM2 with fused scan-apply on A-staging + gelu epilogue ----------------
// out[M][256] = u + gelu( (xloc + a^{j+1}*prefix) @ W2t^T )
__launch_bounds__(256, 2)
__global__ void gemm2_k(const unsigned short* __restrict__ Bu, const unsigned short* __restrict__ B,
                        float* __restrict__ out, const float* __restrict__ u,
                        const float* __restrict__ apw, const float* __restrict__ prefix) {
    __shared__ struct { unsigned short A[128 * 32]; unsigned short B[128 * 32]; } st;
    const int t = threadIdx.x;
    const int bn = blockIdx.x, bm = blockIdx.y;
    const int lane = t & 63;
    const int wm = ((t >> 6) & 1) * 64;
    const int wn = ((t >> 6) >> 1) * 64;
    const int srow = t >> 1, skoff = (t & 1) * 16;
    const unsigned short* Ap = Bu + (size_t)(bm * 128 + srow) * 512 + skoff;
    const unsigned short* Bp = B + (size_t)(bn * 128 + srow) * 512 + skoff;
    const float* fw = apw + srow * 512 + skoff;           // a^{srow+1}, k-interleaved
    const float* pw = prefix + (size_t)bm * 512 + skoff;  // prefix for this chunk
    const int mrow = lane & 15, kq = (lane >> 4) * 8;

    f32x4 acc[4][4] = {};

    for (int k0 = 0; k0 < 512; k0 += 32) {
        uint4 q0 = *(const uint4*)(Ap + k0);
        uint4 q1 = *(const uint4*)(Ap + k0 + 8);
        uint4 b0 = *(const uint4*)(Bp + k0);
        uint4 b1 = *(const uint4*)(Bp + k0 + 8);
        float4 f0 = *(const float4*)(fw + k0),     f1 = *(const float4*)(fw + k0 + 4);
        float4 f2 = *(const float4*)(fw + k0 + 8), f3 = *(const float4*)(fw + k0 + 12);
        float4 g0 = *(const float4*)(pw + k0),     g1 = *(const float4*)(pw + k0 + 4);
        float4 g2 = *(const float4*)(pw + k0 + 8), g3 = *(const float4*)(pw + k0 + 12);
        __syncthreads();
        unsigned int qa[8] = {q0.x, q0.y, q0.z, q0.w, q1.x, q1.y, q1.z, q1.w};
        float fv[16], pv[16];
        *(float4*)&fv[0] = f0;  *(float4*)&fv[4] = f1;  *(float4*)&fv[8] = f2;  *(float4*)&fv[12] = f3;
        *(float4*)&pv[0] = g0;  *(float4*)&pv[4] = g1;  *(float4*)&pv[8] = g2;  *(float4*)&pv[12] = g3;
        unsigned int xo[8];
        #pragma unroll
        for (int e = 0; e < 8; e++) {
            float vr = bf2f(qa[e] & 0xFFFFu), vi = bf2f(qa[e] >> 16);
            float fr = fv[2 * e], fi = fv[2 * e + 1];
            float Pr = pv[2 * e], Pi = pv[2 * e + 1];
            float xr = fmaf(fr, Pr, fmaf(-fi, Pi, vr));
            float xi = fmaf(fr, Pi, fmaf(fi, Pr, vi));
            xo[e] = (unsigned int)f2bf(xr) | ((unsigned int)f2bf(xi) << 16);
        }
        *(uint4*)&st.A[srow * 32 + skoff]     = make_uint4(xo[0], xo[1], xo[2], xo[3]);
        *(uint4*)&st.A[srow * 32 + skoff + 8] = make_uint4(xo[4], xo[5], xo[6], xo[7]);
        *(uint4*)&st.B[srow * 32 + skoff]     = b0;
        *(uint4*)&st.B[srow * 32 + skoff + 8] = b1;
        __syncthreads();
        bf16x8 fa[4], fb[4];
        #pragma unroll
        for (int i = 0; i < 4; i++) {
            fa[i] = *(const bf16x8*)&st.A[(wm + i * 16 + mrow) * 32 + kq];
            fb[i] = *(const bf16x8*)&st.B[(wn + i * 16 + mrow) * 32 + kq];
        }
        #pragma unroll
        for (int i = 0; i < 4; i++)
            #pragma unroll
            for (int j = 0; j < 4; j++)
                acc[i][j] = __builtin_amdgcn_mfma_f32_16x16x32_bf16(fa[i], fb[j], acc[i][j], 0, 0, 0);
    }

    const int r0 = (lane >> 4) * 4, c0 = lane & 15;
    #pragma unroll
    for (int i = 0; i < 4; i++) {
        #pragma unroll
        for (int r = 0; r < 4; r++) {
            const size_t rowoff = (size_t)(bm * 128 + wm + i * 16 + r0 + r) * 256;
            #pragma unroll
            for (int j = 0; j < 4; j++) {
                const int col = bn * 128 + wn + j * 16 + c0;
                float y = acc[i][j][r];
                float z = 0.7978845608f * fmaf(0.044715f * y * y, y, y);
                float e = __expf(2.0f * z);
                float th = 1.0f - 2.0f / (e + 1.0f);
                float g = 0.5f * y * (1.0f + th);
                out[rowoff + col] = u[rowoff + col] + g;
            }
        }
    }
}

extern "C" void kernel_launch(void* const* d_in, const int* in_sizes, int n_in,
                              void* d_out, int out_size, void* d_ws, size_t ws_size,
                              hipStream_t stream) {
    const float* u   = (const float*)d_in[0];
    const float* llr = (const float*)d_in[1];
    const float* lim = (const float*)d_in[2];
    const float* Br  = (const float*)d_in[3];
    const float* Bi  = (const float*)d_in[4];
    const float* Cr  = (const float*)d_in[5];
    const float* Ci  = (const float*)d_in[6];
    const float* ldl = (const float*)d_in[7];
    const float* gam = (const float*)d_in[8];
    const float* bet = (const float*)d_in[9];
    float* out = (float*)d_out;

    float* ws     = (float*)d_ws;
    float* par    = ws;                                   // 1024 floats (a)
    float* apw    = ws + 1024;                            // 128*512 floats (a^{j+1})
    float* last   = apw + 128 * 512;                      // 256*256*2 floats
    float* prefix = last + 256 * 256 * 2;                 // 256*256*2 floats
    unsigned short* W1t = (unsigned short*)(prefix + 256 * 256 * 2);
    unsigned short* W2t = W1t + 512 * HDIM;
    unsigned short* hbf = W2t + HDIM * 512;               // [32768][256] bf16
    unsigned short* Bu  = hbf + (size_t)MTOT * HDIM;      // [32768][512] bf16 (xloc)

    params_k<<<1, PDIM, 0, stream>>>(llr, lim, ldl, par, apw);
    w12_k<<<PDIM, HDIM, 0, stream>>>(Br, Bi, Cr, Ci, llr, lim, ldl, W1t, W2t);
    ln_k<<<MTOT / 4, 256, 0, stream>>>(u, hbf, gam, bet);

    // GEMM1 + zero-seeded chunk scan: Bu = localscan(h @ W1t^T), last = chunk finals
    gemm1_k<<<dim3(4, MTOT / 128), 256, 0, stream>>>(hbf, W1t, Bu, last, par, apw);

    carry_k<<<BATCH, PDIM, 0, stream>>>(last, prefix, apw);

    // GEMM2 + fused prefix-apply + gelu: out = u + gelu((xloc + a^{j+1} prefix) @ W2t^T)
    gemm2_k<<<dim3(2, MTOT / 128), 256, 0, stream>>>(Bu, W2t, out, u, apw, prefix);
}